// Round 6
// baseline (23.553 us; speedup 1.0000x reference)
//
#include <hip/hip_runtime.h>

// Fused NeRF: PE (4 freq) + MLP 27->32->1 via ONE 32x32 bf16 MFMA pair.
// K-axis permuted so each lane builds the B-fragment for ITS OWN point
// (col = lane&31) at 2 frequency bands (k-half = lane>>5). No LDS.
//   h=0: k0..7  = [sin/cos f0 (rows 3..8),  x0 (row0), x1 (row1)]
//        k16..23= [sin/cos f2 (rows 15..20), x2 (row2), bias]
//   h=1: k8..15 = [sin/cos f1 (rows 9..14),  0, 0]
//        k24..31= [sin/cos f3 (rows 21..26), 0, 0]
// W1 rows permuted identically in the A-fragment gather.
// C/D layout (m74/m101): col = lane&31 (point), row = (reg&3)+8*(reg>>2)+4*(lane>>5).

#define NPTS  2097152
#define BLOCK 256
#define TILES 8
#define NBLK  (NPTS / (BLOCK * TILES))   // 1024

typedef __bf16 bf16x8 __attribute__((ext_vector_type(8)));
typedef float  f32x16 __attribute__((ext_vector_type(16)));
typedef float  f32x2  __attribute__((ext_vector_type(2)));

__global__ __launch_bounds__(BLOCK, 6) void nerf_mfma5(
    const float* __restrict__ x,
    const float* __restrict__ W1,
    const float* __restrict__ b1,
    const float* __restrict__ W2,
    const float* __restrict__ b2,
    float* __restrict__ out)
{
    const int tid  = threadIdx.x;
    const int wave = tid >> 6;
    const int lane = tid & 63;
    const int h    = lane >> 5;    // k-half
    const int col  = lane & 31;    // j-row (A) / point-in-group (B)

    const float INV2PI = 0.15915494309189535f;
    const float Fa = (h ? 10.079368f : 1.0f)       * INV2PI;
    const float Fb = (h ? 1024.0f    : 101.59367f) * INV2PI;
    const float eBias = h ? 0.0f : 1.0f;   // bias-row multiplier lives in h=0

    // ---- A fragments (hoisted; W1 rows permuted to my k-order) ----
    bf16x8 a1, a2;
    {
        const int r1 = 3 + 6 * h, r2 = 15 + 6 * h;
        #pragma unroll
        for (int i = 0; i < 6; ++i) {
            a1[i] = (__bf16)W1[(r1 + i) * 32 + col];
            a2[i] = (__bf16)W1[(r2 + i) * 32 + col];
        }
        a1[6] = h ? (__bf16)0.0f : (__bf16)W1[0 * 32 + col];
        a1[7] = h ? (__bf16)0.0f : (__bf16)W1[1 * 32 + col];
        a2[6] = h ? (__bf16)0.0f : (__bf16)W1[2 * 32 + col];
        a2[7] = h ? (__bf16)0.0f : (__bf16)b1[col];
    }

    // ---- layer-2 weights for the C/D rows this lane owns ----
    // pair m covers regs {2m, 2m+1} -> rows {row0, row0+1}
    f32x2 w2p[8];
    #pragma unroll
    for (int m = 0; m < 8; ++m) {
        const int row0 = 8 * (m >> 1) + 4 * h + 2 * (m & 1);
        w2p[m][0] = W2[row0];
        w2p[m][1] = W2[row0 + 1];
    }
    const float bias2 = b2[0];

    const int tb = (blockIdx.x * 4 + wave) * TILES;

    #pragma unroll
    for (int t = 0; t < TILES; ++t) {
        const size_t pbase = (size_t)(tb + t) * 64;
        float SA = 0.0f, SB = 0.0f;

        #pragma unroll
        for (int gr = 0; gr < 2; ++gr) {
            // my point's coords (lanes h=0/1 read same addrs; L1 broadcasts)
            const float* xp = x + (pbase + 32 * gr + col) * 3;
            const float x0 = xp[0], x1 = xp[1], x2 = xp[2];

            // PE at my two bands (revolutions; v_fract + v_sin/v_cos)
            const float aa0 = __builtin_amdgcn_fractf(x0 * Fa);
            const float aa1 = __builtin_amdgcn_fractf(x1 * Fa);
            const float aa2 = __builtin_amdgcn_fractf(x2 * Fa);
            const float ab0 = __builtin_amdgcn_fractf(x0 * Fb);
            const float ab1 = __builtin_amdgcn_fractf(x1 * Fb);
            const float ab2 = __builtin_amdgcn_fractf(x2 * Fb);

            bf16x8 B1, B2;
            B1[0] = (__bf16)__builtin_amdgcn_sinf(aa0);
            B1[1] = (__bf16)__builtin_amdgcn_sinf(aa1);
            B1[2] = (__bf16)__builtin_amdgcn_sinf(aa2);
            B1[3] = (__bf16)__builtin_amdgcn_cosf(aa0);
            B1[4] = (__bf16)__builtin_amdgcn_cosf(aa1);
            B1[5] = (__bf16)__builtin_amdgcn_cosf(aa2);
            B1[6] = (__bf16)(h ? 0.0f : x0);
            B1[7] = (__bf16)(h ? 0.0f : x1);
            B2[0] = (__bf16)__builtin_amdgcn_sinf(ab0);
            B2[1] = (__bf16)__builtin_amdgcn_sinf(ab1);
            B2[2] = (__bf16)__builtin_amdgcn_sinf(ab2);
            B2[3] = (__bf16)__builtin_amdgcn_cosf(ab0);
            B2[4] = (__bf16)__builtin_amdgcn_cosf(ab1);
            B2[5] = (__bf16)__builtin_amdgcn_cosf(ab2);
            B2[6] = (__bf16)(h ? 0.0f : x2);
            B2[7] = (__bf16)eBias;

            // layer 1: K=32 via 2 chained MFMAs; D = [32 j][32 points]
            f32x16 acc = {};
            acc = __builtin_amdgcn_mfma_f32_32x32x16_bf16(a1, B1, acc, 0, 0, 0);
            acc = __builtin_amdgcn_mfma_f32_32x32x16_bf16(a2, B2, acc, 0, 0, 0);

            // layer 2: lane's 16 rows (packed), then one xor32 exchange
            f32x2 ps = {0.0f, 0.0f};
            #pragma unroll
            for (int m = 0; m < 8; ++m) {
                f32x2 v;
                v[0] = fmaxf(acc[2 * m + 0], 0.0f);
                v[1] = fmaxf(acc[2 * m + 1], 0.0f);
                ps = ps + v * w2p[m];
            }
            float p = ps[0] + ps[1];
            p += __shfl_xor(p, 32, 64);   // combine the two k-halves
            if (gr == 0) SA = p; else SB = p;
        }

        // lane&31 == its point's col; lo lanes own group A, hi own group B
        const float S = h ? SB : SA;
        out[pbase + lane] = fmaxf(S + bias2, 0.0f);
    }
}

extern "C" void kernel_launch(void* const* d_in, const int* in_sizes, int n_in,
                              void* d_out, int out_size, void* d_ws, size_t ws_size,
                              hipStream_t stream) {
    const float* x  = (const float*)d_in[0];
    const float* W1 = (const float*)d_in[1];
    const float* b1 = (const float*)d_in[2];
    const float* W2 = (const float*)d_in[3];
    const float* b2 = (const float*)d_in[4];
    float* out = (float*)d_out;

    nerf_mfma5<<<NBLK, BLOCK, 0, stream>>>(x, W1, b1, W2, b2, out);
}

// Round 7
// 19.877 us; speedup vs baseline: 1.1849x; 1.1849x over previous
//
#include <hip/hip_runtime.h>

// Fused NeRF: PE (4 freq) + MLP 27->32->1 via bf16 MFMA (swapped operands).
// R4 structure (per-lane frequency band, no LDS) tuned for 8 waves/SIMD:
// <=64 VGPR via launch_bounds(256,8); 2048 blocks x 4 waves = 8192 waves
// = exactly 8/SIMD chip-wide (perfect residency, no tail).

#define NPTS  2097152
#define BLOCK 256
#define TILES 4
#define NBLK  (NPTS / (BLOCK * TILES))   // 2048

typedef __bf16 bf16x8 __attribute__((ext_vector_type(8)));
typedef float  f32x4  __attribute__((ext_vector_type(4)));
typedef float  f32x2  __attribute__((ext_vector_type(2)));

__global__ __launch_bounds__(BLOCK, 8) void nerf_mfma6(
    const float* __restrict__ x,
    const float* __restrict__ W1,
    const float* __restrict__ b1,
    const float* __restrict__ W2,
    const float* __restrict__ b2,
    float* __restrict__ out)
{
    const int tid  = threadIdx.x;
    const int wave = tid >> 6;
    const int lane = tid & 63;
    const int g    = lane >> 4;   // K-group: this lane's frequency band
    const int c    = lane & 15;   // col-within-16

    // per-lane frequency premultiplied by 1/2pi (v_sin takes revolutions)
    const float INV2PI = 0.15915494309189535f;
    float Fg = 1.0f;
    Fg = (g == 1) ? 10.079368f : Fg;
    Fg = (g == 2) ? 101.59367f : Fg;
    Fg = (g == 3) ? 1024.0f    : Fg;
    Fg *= INV2PI;

    // ---- hoisted A-fragments (W1 rows permuted to per-band k-order) ----
    // k = 8g+i: i<3 -> sin_g(x_i) row 3+6g+i; i<6 -> cos_g row 6+6g+(i-3);
    // i==6 -> g<3 ? x_g row g : bias row; i==7 -> zero pad.
    bf16x8 afrag[2];
    #pragma unroll
    for (int mt = 0; mt < 2; ++mt) {
        const int j = mt * 16 + c;
        #pragma unroll
        for (int i = 0; i < 3; ++i)
            afrag[mt][i] = (__bf16)W1[(3 + 6 * g + i) * 32 + j];
        #pragma unroll
        for (int i = 3; i < 6; ++i)
            afrag[mt][i] = (__bf16)W1[(6 + 6 * g + (i - 3)) * 32 + j];
        afrag[mt][6] = (__bf16)((g < 3) ? W1[g * 32 + j] : b1[j]);
        afrag[mt][7] = (__bf16)0.0f;
    }

    // layer-2 weights for lane's C/D rows: j = mt*16 + g*4 + r
    f32x2 w2p[2][2];
    #pragma unroll
    for (int mt = 0; mt < 2; ++mt)
        #pragma unroll
        for (int rr = 0; rr < 2; ++rr) {
            w2p[mt][rr][0] = W2[mt * 16 + g * 4 + 2 * rr + 0];
            w2p[mt][rr][1] = W2[mt * 16 + g * 4 + 2 * rr + 1];
        }
    const float bias2 = b2[0];

    const int tbase = blockIdx.x * (4 * TILES) + wave * TILES;

    #pragma unroll
    for (int t = 0; t < TILES; ++t) {
        // lane's 4 points: {16*nt + c}, all 3 comps (12 dword loads, batched)
        const float* xb = x + (size_t)(tbase + t) * 192;
        float px[4][3];
        #pragma unroll
        for (int nt = 0; nt < 4; ++nt)
            #pragma unroll
            for (int cm = 0; cm < 3; ++cm)
                px[nt][cm] = xb[(16 * nt + c) * 3 + cm];

        float p[4];
        #pragma unroll
        for (int nt = 0; nt < 4; ++nt) {
            const float x0 = px[nt][0], x1 = px[nt][1], x2 = px[nt][2];

            // PE at this lane's band only (uniform code across the wave)
            const float a0 = __builtin_amdgcn_fractf(x0 * Fg);
            const float a1 = __builtin_amdgcn_fractf(x1 * Fg);
            const float a2 = __builtin_amdgcn_fractf(x2 * Fg);
            float extra = x0;
            extra = (g == 1) ? x1 : extra;
            extra = (g == 2) ? x2 : extra;
            extra = (g == 3) ? 1.0f : extra;

            bf16x8 bf;
            bf[0] = (__bf16)__builtin_amdgcn_sinf(a0);
            bf[1] = (__bf16)__builtin_amdgcn_sinf(a1);
            bf[2] = (__bf16)__builtin_amdgcn_sinf(a2);
            bf[3] = (__bf16)__builtin_amdgcn_cosf(a0);
            bf[4] = (__bf16)__builtin_amdgcn_cosf(a1);
            bf[5] = (__bf16)__builtin_amdgcn_cosf(a2);
            bf[6] = (__bf16)extra;
            bf[7] = (__bf16)0.0f;

            // layer 1: 2 MFMAs (j 0..15, 16..31) over 16 points
            f32x4 acc0 = {0.f, 0.f, 0.f, 0.f};
            f32x4 acc1 = {0.f, 0.f, 0.f, 0.f};
            acc0 = __builtin_amdgcn_mfma_f32_16x16x32_bf16(afrag[0], bf, acc0, 0, 0, 0);
            acc1 = __builtin_amdgcn_mfma_f32_16x16x32_bf16(afrag[1], bf, acc1, 0, 0, 0);

            // layer 2 partials over lane's 8 j's
            f32x2 ps = {0.0f, 0.0f};
            #pragma unroll
            for (int rr = 0; rr < 2; ++rr) {
                f32x2 a;
                a[0] = fmaxf(acc0[2 * rr + 0], 0.0f);
                a[1] = fmaxf(acc0[2 * rr + 1], 0.0f);
                ps = ps + a * w2p[0][rr];
                f32x2 b;
                b[0] = fmaxf(acc1[2 * rr + 0], 0.0f);
                b[1] = fmaxf(acc1[2 * rr + 1], 0.0f);
                ps = ps + b * w2p[1][rr];
            }
            p[nt] = ps[0] + ps[1];
        }

        // select-exchange butterfly: lane ends with its own point (nt = g)
        const bool hi2 = (g >= 2), odd = (g & 1);
        const float s0 = hi2 ? p[0] : p[2];
        const float s1 = hi2 ? p[1] : p[3];
        const float k0 = hi2 ? p[2] : p[0];
        const float k1 = hi2 ? p[3] : p[1];
        const float r0 = k0 + __shfl_xor(s0, 32, 64);
        const float r1 = k1 + __shfl_xor(s1, 32, 64);
        const float uk = odd ? r1 : r0;
        const float us = odd ? r0 : r1;
        const float S  = uk + __shfl_xor(us, 16, 64);

        out[(size_t)(tbase + t) * 64 + lane] = fmaxf(S + bias2, 0.0f);
    }
}

extern "C" void kernel_launch(void* const* d_in, const int* in_sizes, int n_in,
                              void* d_out, int out_size, void* d_ws, size_t ws_size,
                              hipStream_t stream) {
    const float* x  = (const float*)d_in[0];
    const float* W1 = (const float*)d_in[1];
    const float* b1 = (const float*)d_in[2];
    const float* W2 = (const float*)d_in[3];
    const float* b2 = (const float*)d_in[4];
    float* out = (float*)d_out;

    nerf_mfma6<<<NBLK, BLOCK, 0, stream>>>(x, W1, b1, W2, b2, out);
}